// Round 2
// baseline (125.728 us; speedup 1.0000x reference)
//
#include <hip/hip_runtime.h>

typedef __bf16 bf16_t;
typedef __bf16 bf16x8 __attribute__((ext_vector_type(8)));
typedef float  f32x4  __attribute__((ext_vector_type(4)));

#define B_ 16
#define S_ 512
#define H_ 768
#define E_ 19
#define T0 3
#define BM 32            // rows per block
#define NW 6             // waves per block
#define NT (NW*64)       // 384 threads
#define KSTEPS (H_/32)   // 24

// ---- LDS layout (bytes) ----
#define A_OFF   0
#define A_SZ    (BM*H_*2)            // 49152  A tile, bf16, XOR-swizzled
#define LF_OFF  (A_OFF + A_SZ)       // 49152
#define LF_SZ   (E_*H_*4)            // 58368  label_init f32
#define BF_OFF  (LF_OFF + LF_SZ)     // 107520
#define BF_SZ   (H_*4)               // 3072   attn bias f32
#define SP_OFF  (BF_OFF + BF_SZ)     // 110592
#define SP_SZ   (NW*BM*20*4)         // 15360  per-wave partial scores
#define P_OFF   (SP_OFF + SP_SZ)     // 125952
#define P_SZ    (BM*20*4)            // 2560   softmax probs
#define LDS_SZ  (P_OFF + P_SZ)       // 128512

__device__ __forceinline__ float fast_tanh(float x) {
  // tanh(x) = 1 - 2/(1+e^{2x}); safe at +/-large
  float t = __expf(2.0f * x);
  return 1.0f - 2.0f * __builtin_amdgcn_rcpf(t + 1.0f);
}

__global__ void conv_w_kernel(const float* __restrict__ w, bf16_t* __restrict__ o) {
  int i = (blockIdx.x * blockDim.x + threadIdx.x) * 8;
  if (i < H_*H_) {
    float4 u = *(const float4*)(w + i);
    float4 v = *(const float4*)(w + i + 4);
    bf16x8 b;
    b[0]=(bf16_t)u.x; b[1]=(bf16_t)u.y; b[2]=(bf16_t)u.z; b[3]=(bf16_t)u.w;
    b[4]=(bf16_t)v.x; b[5]=(bf16_t)v.y; b[6]=(bf16_t)v.z; b[7]=(bf16_t)v.w;
    *(bf16x8*)(o + i) = b;
  }
}

template <bool WSW>
__global__ __launch_bounds__(NT) void ner_fused(
    const float* __restrict__ seq, const float* __restrict__ lab,
    const float* __restrict__ attw, const float* __restrict__ attb,
    const float* __restrict__ fcw, const int* __restrict__ counts,
    const bf16_t* __restrict__ wbf, float* __restrict__ out)
{
  __shared__ __align__(16) unsigned char smem[LDS_SZ];
  float* Lf = (float*)(smem + LF_OFF);
  float* Bf = (float*)(smem + BF_OFF);
  float* Sp = (float*)(smem + SP_OFF);
  float* Pp = (float*)(smem + P_OFF);

  const int tid   = threadIdx.x;
  const int blk   = blockIdx.x;
  const int batch = blk >> 4;            // 16 blocks per batch (512/32)
  const int s0    = (blk & 15) * BM;
  const size_t rowbase = ((size_t)batch * S_ + s0) * H_;

  // ---- stage A tile (32x768) f32 -> bf16 LDS, XOR-swizzled ----
  {
    const float4* src = (const float4*)(seq + rowbase);
    #pragma unroll
    for (int i = 0; i < (BM*H_/8)/NT; ++i) {          // 8 iters
      int idx = i*NT + tid;
      int row = idx / (H_/8);
      int kv  = idx % (H_/8);
      float4 u = src[row*(H_/4) + kv*2];
      float4 v = src[row*(H_/4) + kv*2 + 1];
      bf16x8 b;
      b[0]=(bf16_t)u.x; b[1]=(bf16_t)u.y; b[2]=(bf16_t)u.z; b[3]=(bf16_t)u.w;
      b[4]=(bf16_t)v.x; b[5]=(bf16_t)v.y; b[6]=(bf16_t)v.z; b[7]=(bf16_t)v.w;
      int byte = row*(H_*2) + kv*16;
      *(bf16x8*)(smem + (byte ^ ((row & 7) << 4))) = b;
    }
  }
  // ---- stage label_init f32 (exact copy) ----
  for (int v = tid; v < E_*H_/4; v += NT)
    ((float4*)Lf)[v] = ((const float4*)lab)[v];
  // ---- stage bias f32 ----
  for (int i = tid; i < H_; i += NT) Bf[i] = attb[i];
  __syncthreads();

  const int lane = tid & 63;
  const int wv   = tid >> 6;
  const int ar   = lane & 15;
  const int kg   = lane >> 4;
  const int wbase = wv * (H_/NW);        // 128 cols per wave

  // ---- GEMM: x_attn tile; acc[m][n][i] = C[m*16+kg*4+i][wbase+n*16+ar] ----
  f32x4 acc[2][8] = {};
  {
    const int a_sw = (ar & 7) << 4;
    #pragma unroll 1
    for (int step = 0; step < KSTEPS; ++step) {
      int kb = step*64 + kg*16;              // byte offset within A row
      bf16x8 a0 = *(const bf16x8*)(smem + ((ar*1536 + kb) ^ a_sw));
      bf16x8 a1 = *(const bf16x8*)(smem + ((16*1536 + ar*1536 + kb) ^ a_sw));
      int k = step*32 + kg*8;
      #pragma unroll
      for (int n = 0; n < 8; ++n) {
        int g = wbase + n*16 + ar;
        bf16x8 bb;
        if constexpr (WSW) {
          bb = *(const bf16x8*)(wbf + (size_t)g*H_ + k);
        } else {
          float4 u = *(const float4*)(attw + (size_t)g*H_ + k);
          float4 v = *(const float4*)(attw + (size_t)g*H_ + k + 4);
          bb[0]=(bf16_t)u.x; bb[1]=(bf16_t)u.y; bb[2]=(bf16_t)u.z; bb[3]=(bf16_t)u.w;
          bb[4]=(bf16_t)v.x; bb[5]=(bf16_t)v.y; bb[6]=(bf16_t)v.z; bb[7]=(bf16_t)v.w;
        }
        acc[0][n] = __builtin_amdgcn_mfma_f32_16x16x32_bf16(a0, bb, acc[0][n], 0,0,0);
        acc[1][n] = __builtin_amdgcn_mfma_f32_16x16x32_bf16(a1, bb, acc[1][n], 0,0,0);
      }
    }
  }

  // ---- per-lane column constants (f32 exact) ----
  float fcv[8], bcol[8];
  #pragma unroll
  for (int n = 0; n < 8; ++n) {
    int col = wbase + n*16 + ar;
    fcv[n]  = fcw[col];
    bcol[n] = Bf[col];
  }

  // ---- scores: s[row][e] = sum_h tanh(x_attn + b + L[e,h]) * fc[h] ----
  for (int e = 0; e < E_; ++e) {
    float lv[8];
    #pragma unroll
    for (int n = 0; n < 8; ++n) lv[n] = Lf[e*H_ + wbase + n*16 + ar] + bcol[n];
    float s8[2][4] = {};
    #pragma unroll
    for (int n = 0; n < 8; ++n)
      #pragma unroll
      for (int m = 0; m < 2; ++m)
        #pragma unroll
        for (int i = 0; i < 4; ++i)
          s8[m][i] += fast_tanh(acc[m][n][i] + lv[n]) * fcv[n];
    #pragma unroll
    for (int off = 1; off < 16; off <<= 1)
      #pragma unroll
      for (int m = 0; m < 2; ++m)
        #pragma unroll
        for (int i = 0; i < 4; ++i)
          s8[m][i] += __shfl_xor(s8[m][i], off, 64);
    if (ar == 0) {
      #pragma unroll
      for (int m = 0; m < 2; ++m)
        #pragma unroll
        for (int i = 0; i < 4; ++i) {
          int row = m*16 + kg*4 + i;
          Sp[(wv*BM + row)*20 + e] = s8[m][i];
        }
    }
  }
  __syncthreads();

  // ---- softmax over E=19, rows spread across all waves ----
  if (tid % 12 == 0) {
    int row = tid / 12;                 // 0..31
    float sc[E_];
    float mx = -1e30f;
    #pragma unroll
    for (int e = 0; e < E_; ++e) {
      float v = 0.f;
      #pragma unroll
      for (int w2 = 0; w2 < NW; ++w2) v += Sp[(w2*BM + row)*20 + e];
      sc[e] = v;
      mx = fmaxf(mx, v);
    }
    float ssum = 0.f;
    #pragma unroll
    for (int e = 0; e < E_; ++e) {
      float p = __expf(sc[e] - mx);
      sc[e] = p; ssum += p;
    }
    float r = __builtin_amdgcn_rcpf(ssum);
    #pragma unroll
    for (int e = 0; e < E_; ++e) Pp[row*20 + e] = sc[e]*r;
  }
  __syncthreads();

  // ---- ctx + residual + keep-mask + store (f32 out) ----
  {
    const int cg = tid % 96;             // column group of 8 floats
    const int rq = tid / 96;             // row quarter (8 rows)
    float o[8][8] = {};
    const f32x4* L4 = (const f32x4*)Lf;
    for (int e = 0; e < E_; ++e) {
      f32x4 la = L4[e*(H_/4) + cg*2];
      f32x4 lb = L4[e*(H_/4) + cg*2 + 1];
      #pragma unroll
      for (int r = 0; r < 8; ++r) {
        float p = Pp[(rq*8 + r)*20 + e];   // LDS broadcast
        o[r][0] += p*la[0]; o[r][1] += p*la[1]; o[r][2] += p*la[2]; o[r][3] += p*la[3];
        o[r][4] += p*lb[0]; o[r][5] += p*lb[1]; o[r][6] += p*lb[2]; o[r][7] += p*lb[3];
      }
    }
    const int cnt = counts[batch];
    #pragma unroll
    for (int r = 0; r < 8; ++r) {
      int row = rq*8 + r;
      int s   = s0 + row;
      bool keep = (s >= T0) && (s < cnt + T0);
      size_t idx = rowbase + (size_t)row*H_ + cg*8;
      float4 s1 = *(const float4*)(seq + idx);
      float4 s2 = *(const float4*)(seq + idx + 4);
      float4 o1, o2;
      if (keep) {
        o1 = s1; o2 = s2;                 // bit-exact passthrough
      } else {
        o1 = make_float4(s1.x + o[r][0], s1.y + o[r][1], s1.z + o[r][2], s1.w + o[r][3]);
        o2 = make_float4(s2.x + o[r][4], s2.y + o[r][5], s2.z + o[r][6], s2.w + o[r][7]);
      }
      *(float4*)(out + idx)     = o1;
      *(float4*)(out + idx + 4) = o2;
    }
  }
}

extern "C" void kernel_launch(void* const* d_in, const int* in_sizes, int n_in,
                              void* d_out, int out_size, void* d_ws, size_t ws_size,
                              hipStream_t stream) {
  const float* seq    = (const float*)d_in[0];
  const float* lab    = (const float*)d_in[1];
  const float* attw   = (const float*)d_in[2];
  const float* attb   = (const float*)d_in[3];
  const float* fcw    = (const float*)d_in[4];
  const int*   counts = (const int*)d_in[5];
  float* out = (float*)d_out;
  dim3 grid((B_*S_)/BM), block(NT);

  if (ws_size >= (size_t)(H_*H_*sizeof(bf16_t))) {
    bf16_t* wbf = (bf16_t*)d_ws;
    conv_w_kernel<<<dim3((H_*H_/8 + 255)/256), dim3(256), 0, stream>>>(attw, wbf);
    ner_fused<true><<<grid, block, 0, stream>>>(seq, lab, attw, attb, fcw, counts, wbf, out);
  } else {
    ner_fused<false><<<grid, block, 0, stream>>>(seq, lab, attw, attb, fcw, counts, nullptr, out);
  }
}

// Round 3
// 120.173 us; speedup vs baseline: 1.0462x; 1.0462x over previous
//
#include <hip/hip_runtime.h>

typedef __bf16 bf16_t;
typedef __bf16 bf16x8 __attribute__((ext_vector_type(8)));
typedef _Float16 f16x8 __attribute__((ext_vector_type(8)));
typedef float  f32x4  __attribute__((ext_vector_type(4)));

#define B_ 16
#define S_ 512
#define H_ 768
#define E_ 19
#define T0 3
#define BM 16            // rows per block
#define NW 6             // waves per block
#define NT (NW*64)       // 384 threads
#define KSTEPS (H_/32)   // 24
#define SCAL 2.8853900817779268f   // 2*log2(e)

// ---- LDS layout (bytes) ----
// live set 1 (stage+GEMM): A tile (bf16, swizzled) + Ls
// live set 2 (scores on):  Sp/Pp alias into the A region (barrier-protected)
#define A_SZ   (BM*H_*2)          // 24576
#define LS_OFF A_SZ               // 24576
#define LS_SZ  (E_*H_*2)          // 29184  Ls = 2log2e*(L+b), f16, wave-permuted
#define LDS_SZ (A_SZ + LS_SZ)     // 53760  -> 2 blocks/CU
#define SP_OFF 0                  // [NW][BM][20] f32 = 7680
#define PP_OFF (NW*BM*20*4)       // 7680; [BM][20] f32 = 1280

__global__ void conv_w_kernel(const float* __restrict__ w, bf16_t* __restrict__ o) {
  int i = (blockIdx.x * blockDim.x + threadIdx.x) * 8;
  if (i < H_*H_) {
    float4 u = *(const float4*)(w + i);
    float4 v = *(const float4*)(w + i + 4);
    bf16x8 b;
    b[0]=(bf16_t)(u.x*SCAL); b[1]=(bf16_t)(u.y*SCAL); b[2]=(bf16_t)(u.z*SCAL); b[3]=(bf16_t)(u.w*SCAL);
    b[4]=(bf16_t)(v.x*SCAL); b[5]=(bf16_t)(v.y*SCAL); b[6]=(bf16_t)(v.z*SCAL); b[7]=(bf16_t)(v.w*SCAL);
    *(bf16x8*)(o + i) = b;
  }
}

template <bool WSW>
__global__ __launch_bounds__(NT, 3) void ner_fused(
    const float* __restrict__ seq, const float* __restrict__ lab,
    const float* __restrict__ attw, const float* __restrict__ attb,
    const float* __restrict__ fcw, const int* __restrict__ counts,
    const bf16_t* __restrict__ wbf, float* __restrict__ out)
{
  __shared__ __align__(16) unsigned char smem[LDS_SZ];
  _Float16* Lsh = (_Float16*)(smem + LS_OFF);
  float* Sp = (float*)(smem + SP_OFF);
  float* Pp = (float*)(smem + PP_OFF);

  const int tid   = threadIdx.x;
  const int blk   = blockIdx.x;
  const int batch = blk >> 5;            // 32 blocks per batch (512/16)
  const int s0    = (blk & 31) * BM;
  const size_t rowbase = ((size_t)batch * S_ + s0) * H_;

  // ---- stage A tile (16x768) f32 -> bf16 LDS, XOR-swizzled ----
  {
    const float4* src = (const float4*)(seq + rowbase);
    #pragma unroll
    for (int i = 0; i < (BM*H_/8)/NT; ++i) {          // 4 iters
      int idx = i*NT + tid;
      int row = idx / (H_/8);
      int kv  = idx % (H_/8);
      float4 u = src[row*(H_/4) + kv*2];
      float4 v = src[row*(H_/4) + kv*2 + 1];
      bf16x8 b;
      b[0]=(bf16_t)u.x; b[1]=(bf16_t)u.y; b[2]=(bf16_t)u.z; b[3]=(bf16_t)u.w;
      b[4]=(bf16_t)v.x; b[5]=(bf16_t)v.y; b[6]=(bf16_t)v.z; b[7]=(bf16_t)v.w;
      int byte = row*(H_*2) + kv*16;
      *(bf16x8*)(smem + (byte ^ ((row & 7) << 4))) = b;
    }
  }
  // ---- stage Ls = 2log2e*(L+b) as f16, wave-permuted:
  //      idx ((e*NW + wv)*16 + ar)*8 + n  <->  col = wv*128 + n*16 + ar ----
  for (int i = tid*4; i < E_*H_; i += NT*4) {
    int c = i % H_;                       // 4 consecutive cols
    float4 l4 = *(const float4*)(lab + i);
    float4 b4 = *(const float4*)(attb + c);
    int e = i / H_;
    #pragma unroll
    for (int j = 0; j < 4; ++j) {
      int col = c + j;
      int wv2 = col >> 7, r = col & 127, n = r >> 4, arr = r & 15;
      float v = ((&l4.x)[j] + (&b4.x)[j]) * SCAL;
      Lsh[((e*NW + wv2)*16 + arr)*8 + n] = (_Float16)v;
    }
  }
  __syncthreads();

  const int lane = tid & 63;
  const int wv   = tid >> 6;
  const int ar   = lane & 15;
  const int kg   = lane >> 4;
  const int wbase = wv * (H_/NW);        // 128 cols per wave

  // ---- GEMM: acc[n][i] = 2log2e * x_attn[row = kg*4+i][col = wbase+n*16+ar] ----
  f32x4 acc[8] = {};
  {
    const int a_sw = (ar & 7) << 4;
    #pragma unroll 1
    for (int step = 0; step < KSTEPS; ++step) {
      int kb = step*64 + kg*16;
      bf16x8 a0 = *(const bf16x8*)(smem + ((ar*1536 + kb) ^ a_sw));
      int k = step*32 + kg*8;
      #pragma unroll
      for (int n = 0; n < 8; ++n) {
        int g = wbase + n*16 + ar;
        bf16x8 bb;
        if constexpr (WSW) {
          bb = *(const bf16x8*)(wbf + (size_t)g*H_ + k);
        } else {
          float4 u = *(const float4*)(attw + (size_t)g*H_ + k);
          float4 v = *(const float4*)(attw + (size_t)g*H_ + k + 4);
          bb[0]=(bf16_t)(u.x*SCAL); bb[1]=(bf16_t)(u.y*SCAL); bb[2]=(bf16_t)(u.z*SCAL); bb[3]=(bf16_t)(u.w*SCAL);
          bb[4]=(bf16_t)(v.x*SCAL); bb[5]=(bf16_t)(v.y*SCAL); bb[6]=(bf16_t)(v.z*SCAL); bb[7]=(bf16_t)(v.w*SCAL);
        }
        acc[n] = __builtin_amdgcn_mfma_f32_16x16x32_bf16(a0, bb, acc[n], 0,0,0);
      }
    }
  }
  __syncthreads();   // all waves done with A region; Sp may now alias it

  // ---- per-lane fc (f32 exact) ----
  float fcv[8];
  #pragma unroll
  for (int n = 0; n < 8; ++n) fcv[n] = fcw[wbase + n*16 + ar];

  // ---- scores: S[row][e] = sum_h fc[h] / (1 + e^{2x});  logits = -2*S ----
  {
    const _Float16* Lw = Lsh + (wv*16 + ar)*8;
    #pragma unroll 1
    for (int e = 0; e < E_; ++e) {
      f16x8 lh = *(const f16x8*)(Lw + e*(NW*128));
      float lv[8];
      #pragma unroll
      for (int n = 0; n < 8; ++n) lv[n] = (float)lh[n];
      float s8[4] = {};
      #pragma unroll
      for (int n = 0; n < 8; ++n)
        #pragma unroll
        for (int i = 0; i < 4; ++i) {
          float t = __builtin_amdgcn_exp2f(acc[n][i] + lv[n]);
          s8[i] += fcv[n] * __builtin_amdgcn_rcpf(t + 1.0f);
        }
      #pragma unroll
      for (int off = 1; off < 16; off <<= 1)
        #pragma unroll
        for (int i = 0; i < 4; ++i)
          s8[i] += __shfl_xor(s8[i], off, 64);
      if (ar == 0) {
        #pragma unroll
        for (int i = 0; i < 4; ++i)
          Sp[(wv*BM + kg*4 + i)*20 + e] = s8[i];
      }
    }
  }
  __syncthreads();

  // ---- softmax over E=19 (logits = -2*S), rows spread across waves ----
  if (tid % 24 == 0) {
    int row = tid / 24;                  // 0..15
    float sc[E_];
    float mx = -1e30f;
    #pragma unroll
    for (int e = 0; e < E_; ++e) {
      float v = 0.f;
      #pragma unroll
      for (int w2 = 0; w2 < NW; ++w2) v += Sp[(w2*BM + row)*20 + e];
      sc[e] = -2.0f * v;
      mx = fmaxf(mx, sc[e]);
    }
    float ssum = 0.f;
    #pragma unroll
    for (int e = 0; e < E_; ++e) {
      float p = __builtin_amdgcn_exp2f((sc[e] - mx) * 1.4426950408889634f);
      sc[e] = p; ssum += p;
    }
    float r = __builtin_amdgcn_rcpf(ssum);
    #pragma unroll
    for (int e = 0; e < E_; ++e) Pp[row*20 + e] = sc[e]*r;
  }
  __syncthreads();

  // ---- ctx + residual + keep-mask + store (f32), L read from global (L2) ----
  {
    const int cg = tid % 96;             // column group of 8 floats
    const int rq = tid / 96;             // 4 rows each
    float o[4][8] = {};
    const f32x4* L4 = (const f32x4*)lab;
    #pragma unroll 1
    for (int e = 0; e < E_; ++e) {
      f32x4 la = L4[e*(H_/4) + cg*2];
      f32x4 lb = L4[e*(H_/4) + cg*2 + 1];
      #pragma unroll
      for (int r = 0; r < 4; ++r) {
        float p = Pp[(rq*4 + r)*20 + e];   // LDS broadcast
        o[r][0] += p*la[0]; o[r][1] += p*la[1]; o[r][2] += p*la[2]; o[r][3] += p*la[3];
        o[r][4] += p*lb[0]; o[r][5] += p*lb[1]; o[r][6] += p*lb[2]; o[r][7] += p*lb[3];
      }
    }
    const int cnt = counts[batch];
    #pragma unroll
    for (int r = 0; r < 4; ++r) {
      int row = rq*4 + r;
      int s   = s0 + row;
      bool keep = (s >= T0) && (s < cnt + T0);
      size_t idx = rowbase + (size_t)row*H_ + cg*8;
      float4 s1 = *(const float4*)(seq + idx);
      float4 s2 = *(const float4*)(seq + idx + 4);
      float4 o1, o2;
      if (keep) {
        o1 = s1; o2 = s2;                 // bit-exact passthrough
      } else {
        o1 = make_float4(s1.x + o[r][0], s1.y + o[r][1], s1.z + o[r][2], s1.w + o[r][3]);
        o2 = make_float4(s2.x + o[r][4], s2.y + o[r][5], s2.z + o[r][6], s2.w + o[r][7]);
      }
      *(float4*)(out + idx)     = o1;
      *(float4*)(out + idx + 4) = o2;
    }
  }
}

extern "C" void kernel_launch(void* const* d_in, const int* in_sizes, int n_in,
                              void* d_out, int out_size, void* d_ws, size_t ws_size,
                              hipStream_t stream) {
  const float* seq    = (const float*)d_in[0];
  const float* lab    = (const float*)d_in[1];
  const float* attw   = (const float*)d_in[2];
  const float* attb   = (const float*)d_in[3];
  const float* fcw    = (const float*)d_in[4];
  const int*   counts = (const int*)d_in[5];
  float* out = (float*)d_out;
  dim3 grid((B_*S_)/BM), block(NT);

  if (ws_size >= (size_t)(H_*H_*sizeof(bf16_t))) {
    bf16_t* wbf = (bf16_t*)d_ws;
    conv_w_kernel<<<dim3((H_*H_/8 + 255)/256), dim3(256), 0, stream>>>(attw, wbf);
    ner_fused<true><<<grid, block, 0, stream>>>(seq, lab, attw, attb, fcw, counts, wbf, out);
  } else {
    ner_fused<false><<<grid, block, 0, stream>>>(seq, lab, attw, attb, fcw, counts, nullptr, out);
  }
}

// Round 4
// 95.898 us; speedup vs baseline: 1.3111x; 1.2531x over previous
//
#include <hip/hip_runtime.h>

typedef __bf16 bf16_t;
typedef __bf16 bf16x8 __attribute__((ext_vector_type(8)));
typedef _Float16 f16_t;
typedef _Float16 f16x8 __attribute__((ext_vector_type(8)));
typedef float  f32x4  __attribute__((ext_vector_type(4)));

#define B_ 16
#define S_ 512
#define H_ 768
#define E_ 19
#define T0 3
#define ROWS (B_*S_)
#define SCAL 2.8853900817779268f   // 2*log2(e)

// ---- workspace layout (bytes) ----
#define WS_W_OFF  0
#define WS_W_SZ   (H_*H_*2)                 // 1179648  W bf16 prescaled
#define WS_LS_OFF (WS_W_OFF + WS_W_SZ)
#define WS_LS_SZ  (E_*H_*2)                 // 29184    Ls f16 = SCAL*(L+b)
#define WS_XS_OFF (WS_LS_OFF + WS_LS_SZ)
#define WS_XS_SZ  (ROWS*H_*2)               // 12582912 xs f16 = SCAL*(xW^T+b)
#define WS_NEED   (WS_XS_OFF + WS_XS_SZ)

// ================= prep: W -> bf16*SCAL ; Ls table =================
__global__ __launch_bounds__(256) void prep_kernel(
    const float* __restrict__ w, const float* __restrict__ lab,
    const float* __restrict__ attb, bf16_t* __restrict__ wbf,
    f16_t* __restrict__ lsg) {
  int t = blockIdx.x*256 + threadIdx.x;
  int i = t*8;
  if (i < H_*H_) {
    float4 u = *(const float4*)(w + i);
    float4 v = *(const float4*)(w + i + 4);
    bf16x8 b;
    b[0]=(bf16_t)(u.x*SCAL); b[1]=(bf16_t)(u.y*SCAL); b[2]=(bf16_t)(u.z*SCAL); b[3]=(bf16_t)(u.w*SCAL);
    b[4]=(bf16_t)(v.x*SCAL); b[5]=(bf16_t)(v.y*SCAL); b[6]=(bf16_t)(v.z*SCAL); b[7]=(bf16_t)(v.w*SCAL);
    *(bf16x8*)(wbf + i) = b;
  }
  if (t < E_*H_) {
    int col = t % H_;
    lsg[t] = (f16_t)((lab[t] + attb[col]) * SCAL);
  }
}

// ================= K1: GEMM -> xs f16 =================
// BM=32 rows/block, 12 waves x 64 cols, 256 blocks
#define K1_BM 32
#define K1_NT 768
__global__ __launch_bounds__(K1_NT) void gemm_xs(
    const float* __restrict__ seq, const float* __restrict__ attb,
    const bf16_t* __restrict__ wbf, f16_t* __restrict__ xs) {
  __shared__ __align__(16) unsigned char smem[K1_BM*H_*2];   // 49152
  const int tid = threadIdx.x;
  const size_t rowbase = (size_t)blockIdx.x * K1_BM * H_;

  { // stage A f32 -> bf16, XOR-swizzled
    const float4* src = (const float4*)(seq + rowbase);
    #pragma unroll
    for (int i = 0; i < (K1_BM*H_/8)/K1_NT; ++i) {   // 4 iters
      int idx = i*K1_NT + tid;
      int row = idx / (H_/8);
      int kv  = idx % (H_/8);
      float4 u = src[row*(H_/4) + kv*2];
      float4 v = src[row*(H_/4) + kv*2 + 1];
      bf16x8 b;
      b[0]=(bf16_t)u.x; b[1]=(bf16_t)u.y; b[2]=(bf16_t)u.z; b[3]=(bf16_t)u.w;
      b[4]=(bf16_t)v.x; b[5]=(bf16_t)v.y; b[6]=(bf16_t)v.z; b[7]=(bf16_t)v.w;
      int byte = row*(H_*2) + kv*16;
      *(bf16x8*)(smem + (byte ^ ((row & 7) << 4))) = b;
    }
  }
  __syncthreads();

  const int lane = tid & 63, wv = tid >> 6;
  const int ar = lane & 15, kg = lane >> 4;
  const int wbase = wv * 64;            // 64 cols per wave
  f32x4 acc[2][4] = {};
  const int a_sw = (ar & 7) << 4;
  #pragma unroll 1
  for (int step = 0; step < H_/32; ++step) {
    int kb = step*64 + kg*16;
    bf16x8 a0 = *(const bf16x8*)(smem + ((ar*1536 + kb) ^ a_sw));
    bf16x8 a1 = *(const bf16x8*)(smem + ((16*1536 + ar*1536 + kb) ^ a_sw));
    int k = step*32 + kg*8;
    #pragma unroll
    for (int n = 0; n < 4; ++n) {
      bf16x8 bb = *(const bf16x8*)(wbf + (size_t)(wbase + n*16 + ar)*H_ + k);
      acc[0][n] = __builtin_amdgcn_mfma_f32_16x16x32_bf16(a0, bb, acc[0][n], 0,0,0);
      acc[1][n] = __builtin_amdgcn_mfma_f32_16x16x32_bf16(a1, bb, acc[1][n], 0,0,0);
    }
  }
  // epilogue: xs[row][col] = f16(acc + SCAL*attb[col])
  #pragma unroll
  for (int n = 0; n < 4; ++n) {
    int col = wbase + n*16 + ar;
    float bc = attb[col] * SCAL;
    #pragma unroll
    for (int m = 0; m < 2; ++m)
      #pragma unroll
      for (int i2 = 0; i2 < 4; ++i2) {
        int row = m*16 + kg*4 + i2;
        xs[rowbase + (size_t)row*H_ + col] = (f16_t)(acc[m][n][i2] + bc);
      }
  }
}

// ================= K2: score + softmax + ctx =================
// 2048 blocks x 256 thr; 4 rows/block; group(g=tid/16): r=g&3, eq=g>>2
#define K2_R   4
#define K2_PAD 1552                      // LDS row stride (bank-spread)
#define K2_SALL (K2_R*K2_PAD)            // 6208
#define K2_PP   (K2_SALL + K2_R*20*4)    // 6528
#define K2_LDS  (K2_PP + K2_R*20*4)      // 6848
__global__ __launch_bounds__(256, 8) void score_ctx(
    const f16_t* __restrict__ xs, const f16_t* __restrict__ lsg,
    const float* __restrict__ fcw, const float* __restrict__ seq,
    const float* __restrict__ lab, const int* __restrict__ counts,
    float* __restrict__ out) {
  __shared__ __align__(16) unsigned char smem[K2_LDS];
  float* Sall = (float*)(smem + K2_SALL);
  float* Pp   = (float*)(smem + K2_PP);
  const int tid = threadIdx.x;
  const int r0  = blockIdx.x * K2_R;     // global row base

  // stage xs rows (f16), padded stride
  for (int i = tid; i < K2_R*(H_/8); i += 256) {   // 384 chunks
    int row = i / (H_/8), kv = i % (H_/8);
    f16x8 v = *(const f16x8*)(xs + (size_t)(r0 + row)*H_ + kv*8);
    *(f16x8*)(smem + row*K2_PAD + kv*16) = v;
  }
  __syncthreads();

  const int g = tid >> 4, k = tid & 15;
  const int r = g & 3, eq = g >> 2;
  const f16_t* xrow = (const f16_t*)(smem + r*K2_PAD + k*96);

  float sc[5];
  #pragma unroll 1
  for (int j = 0; j < 5; ++j) {
    int e = eq*5 + j;
    if (e >= E_) { sc[j] = 0.f; continue; }
    const f16_t* lrow = lsg + e*H_ + k*48;
    float s = 0.f;
    #pragma unroll
    for (int c = 0; c < 6; ++c) {
      f16x8 xh = *(const f16x8*)(xrow + c*8);
      f16x8 lh = *(const f16x8*)(lrow + c*8);
      f32x4 f0 = *(const f32x4*)(fcw + k*48 + c*8);
      f32x4 f1 = *(const f32x4*)(fcw + k*48 + c*8 + 4);
      #pragma unroll
      for (int q = 0; q < 8; ++q) {
        float arg = (float)xh[q] + (float)lh[q];
        float t = __builtin_amdgcn_exp2f(arg);
        float fcq = (q < 4) ? f0[q] : f1[q-4];
        s += fcq * __builtin_amdgcn_rcpf(t + 1.0f);   // fc * sigma(-2x)
      }
    }
    #pragma unroll
    for (int off = 1; off < 16; off <<= 1) s += __shfl_xor(s, off, 64);
    sc[j] = s;
  }
  if (k == 0) {
    #pragma unroll
    for (int j = 0; j < 5; ++j) {
      int e = eq*5 + j;
      if (e < E_) Sall[r*20 + e] = sc[j];
    }
  }
  __syncthreads();

  // softmax per row (logits = -2*S, const shift drops out)
  if (tid < K2_R) {
    float s2[E_]; float mx = -1e30f;
    #pragma unroll
    for (int e = 0; e < E_; ++e) {
      float v = -2.0f * Sall[tid*20 + e];
      s2[e] = v; mx = fmaxf(mx, v);
    }
    float ssum = 0.f;
    #pragma unroll
    for (int e = 0; e < E_; ++e) {
      float p = __builtin_amdgcn_exp2f((s2[e] - mx) * 1.4426950408889634f);
      s2[e] = p; ssum += p;
    }
    float rr = __builtin_amdgcn_rcpf(ssum);
    #pragma unroll
    for (int e = 0; e < E_; ++e) Pp[tid*20 + e] = s2[e]*rr;
  }
  __syncthreads();

  // ctx + residual + keep-mask; 192 threads own one float4-col each, 4 rows
  if (tid < 192) {
    f32x4 o4[K2_R] = {};
    #pragma unroll 1
    for (int e = 0; e < E_; ++e) {
      f32x4 la = *(const f32x4*)(lab + e*H_ + tid*4);
      #pragma unroll
      for (int rr2 = 0; rr2 < K2_R; ++rr2) {
        float p = Pp[rr2*20 + e];
        o4[rr2] += p * la;
      }
    }
    const int batch = r0 >> 9;
    const int cnt = counts[batch];
    #pragma unroll
    for (int rr2 = 0; rr2 < K2_R; ++rr2) {
      int row = r0 + rr2;
      int s   = row & 511;
      bool keep = (s >= T0) && (s < cnt + T0);
      size_t idx = (size_t)row*H_ + tid*4;
      f32x4 sv = *(const f32x4*)(seq + idx);
      f32x4 ov = keep ? sv : (sv + o4[rr2]);
      *(f32x4*)(out + idx) = ov;
    }
  }
}

// ================= fallback: round-3 fused kernel (passed) =================
#define BM 16
#define NW 6
#define NT (NW*64)
#define A_SZ   (BM*H_*2)
#define LS_OFF A_SZ
#define LS_SZ  (E_*H_*2)
#define LDS_SZ (A_SZ + LS_SZ)
#define SP_OFF 0
#define PP_OFF (NW*BM*20*4)

template <bool WSW>
__global__ __launch_bounds__(NT, 3) void ner_fused(
    const float* __restrict__ seq, const float* __restrict__ lab,
    const float* __restrict__ attw, const float* __restrict__ attb,
    const float* __restrict__ fcw, const int* __restrict__ counts,
    const bf16_t* __restrict__ wbf, float* __restrict__ out)
{
  __shared__ __align__(16) unsigned char smem[LDS_SZ];
  _Float16* Lsh = (_Float16*)(smem + LS_OFF);
  float* Sp = (float*)(smem + SP_OFF);
  float* Pp = (float*)(smem + PP_OFF);
  const int tid   = threadIdx.x;
  const int blk   = blockIdx.x;
  const int batch = blk >> 5;
  const int s0    = (blk & 31) * BM;
  const size_t rowbase = ((size_t)batch * S_ + s0) * H_;
  {
    const float4* src = (const float4*)(seq + rowbase);
    #pragma unroll
    for (int i = 0; i < (BM*H_/8)/NT; ++i) {
      int idx = i*NT + tid;
      int row = idx / (H_/8);
      int kv  = idx % (H_/8);
      float4 u = src[row*(H_/4) + kv*2];
      float4 v = src[row*(H_/4) + kv*2 + 1];
      bf16x8 b;
      b[0]=(bf16_t)u.x; b[1]=(bf16_t)u.y; b[2]=(bf16_t)u.z; b[3]=(bf16_t)u.w;
      b[4]=(bf16_t)v.x; b[5]=(bf16_t)v.y; b[6]=(bf16_t)v.z; b[7]=(bf16_t)v.w;
      int byte = row*(H_*2) + kv*16;
      *(bf16x8*)(smem + (byte ^ ((row & 7) << 4))) = b;
    }
  }
  for (int i = tid*4; i < E_*H_; i += NT*4) {
    int c = i % H_;
    float4 l4 = *(const float4*)(lab + i);
    float4 b4 = *(const float4*)(attb + c);
    int e = i / H_;
    #pragma unroll
    for (int j = 0; j < 4; ++j) {
      int col = c + j;
      int wv2 = col >> 7, rr = col & 127, n = rr >> 4, arr = rr & 15;
      float v = ((&l4.x)[j] + (&b4.x)[j]) * SCAL;
      Lsh[((e*NW + wv2)*16 + arr)*8 + n] = (_Float16)v;
    }
  }
  __syncthreads();
  const int lane = tid & 63;
  const int wv   = tid >> 6;
  const int ar   = lane & 15;
  const int kg   = lane >> 4;
  const int wbase = wv * (H_/NW);
  f32x4 acc[8] = {};
  {
    const int a_sw = (ar & 7) << 4;
    #pragma unroll 1
    for (int step = 0; step < H_/32; ++step) {
      int kb = step*64 + kg*16;
      bf16x8 a0 = *(const bf16x8*)(smem + ((ar*1536 + kb) ^ a_sw));
      int k = step*32 + kg*8;
      #pragma unroll
      for (int n = 0; n < 8; ++n) {
        int gcol = wbase + n*16 + ar;
        bf16x8 bb;
        if constexpr (WSW) {
          bb = *(const bf16x8*)(wbf + (size_t)gcol*H_ + k);
        } else {
          float4 u = *(const float4*)(attw + (size_t)gcol*H_ + k);
          float4 v = *(const float4*)(attw + (size_t)gcol*H_ + k + 4);
          bb[0]=(bf16_t)(u.x*SCAL); bb[1]=(bf16_t)(u.y*SCAL); bb[2]=(bf16_t)(u.z*SCAL); bb[3]=(bf16_t)(u.w*SCAL);
          bb[4]=(bf16_t)(v.x*SCAL); bb[5]=(bf16_t)(v.y*SCAL); bb[6]=(bf16_t)(v.z*SCAL); bb[7]=(bf16_t)(v.w*SCAL);
        }
        acc[n] = __builtin_amdgcn_mfma_f32_16x16x32_bf16(a0, bb, acc[n], 0,0,0);
      }
    }
  }
  __syncthreads();
  float fcv[8];
  #pragma unroll
  for (int n = 0; n < 8; ++n) fcv[n] = fcw[wbase + n*16 + ar];
  {
    const _Float16* Lw = Lsh + (wv*16 + ar)*8;
    #pragma unroll 1
    for (int e = 0; e < E_; ++e) {
      f16x8 lh = *(const f16x8*)(Lw + e*(NW*128));
      float lv[8];
      #pragma unroll
      for (int n = 0; n < 8; ++n) lv[n] = (float)lh[n];
      float s8[4] = {};
      #pragma unroll
      for (int n = 0; n < 8; ++n)
        #pragma unroll
        for (int i = 0; i < 4; ++i) {
          float t = __builtin_amdgcn_exp2f(acc[n][i] + lv[n]);
          s8[i] += fcv[n] * __builtin_amdgcn_rcpf(t + 1.0f);
        }
      #pragma unroll
      for (int off = 1; off < 16; off <<= 1)
        #pragma unroll
        for (int i = 0; i < 4; ++i)
          s8[i] += __shfl_xor(s8[i], off, 64);
      if (ar == 0) {
        #pragma unroll
        for (int i = 0; i < 4; ++i)
          Sp[(wv*BM + kg*4 + i)*20 + e] = s8[i];
      }
    }
  }
  __syncthreads();
  if (tid % 24 == 0) {
    int row = tid / 24;
    float sc2[E_];
    float mx = -1e30f;
    #pragma unroll
    for (int e = 0; e < E_; ++e) {
      float v = 0.f;
      #pragma unroll
      for (int w2 = 0; w2 < NW; ++w2) v += Sp[(w2*BM + row)*20 + e];
      sc2[e] = -2.0f * v;
      mx = fmaxf(mx, sc2[e]);
    }
    float ssum = 0.f;
    #pragma unroll
    for (int e = 0; e < E_; ++e) {
      float p = __builtin_amdgcn_exp2f((sc2[e] - mx) * 1.4426950408889634f);
      sc2[e] = p; ssum += p;
    }
    float rr = __builtin_amdgcn_rcpf(ssum);
    #pragma unroll
    for (int e = 0; e < E_; ++e) Pp[row*20 + e] = sc2[e]*rr;
  }
  __syncthreads();
  {
    const int cg = tid % 96;
    const int rq = tid / 96;
    float o[4][8] = {};
    const f32x4* L4 = (const f32x4*)lab;
    #pragma unroll 1
    for (int e = 0; e < E_; ++e) {
      f32x4 la = L4[e*(H_/4) + cg*2];
      f32x4 lb = L4[e*(H_/4) + cg*2 + 1];
      #pragma unroll
      for (int rr2 = 0; rr2 < 4; ++rr2) {
        float p = Pp[(rq*4 + rr2)*20 + e];
        o[rr2][0] += p*la[0]; o[rr2][1] += p*la[1]; o[rr2][2] += p*la[2]; o[rr2][3] += p*la[3];
        o[rr2][4] += p*lb[0]; o[rr2][5] += p*lb[1]; o[rr2][6] += p*lb[2]; o[rr2][7] += p*lb[3];
      }
    }
    const int cnt = counts[batch];
    #pragma unroll
    for (int rr2 = 0; rr2 < 4; ++rr2) {
      int row = rq*4 + rr2;
      int s   = s0 + row;
      bool keep = (s >= T0) && (s < cnt + T0);
      size_t idx = rowbase + (size_t)row*H_ + cg*8;
      float4 s1 = *(const float4*)(seq + idx);
      float4 s2v = *(const float4*)(seq + idx + 4);
      float4 o1, o2;
      if (keep) { o1 = s1; o2 = s2v; }
      else {
        o1 = make_float4(s1.x + o[rr2][0], s1.y + o[rr2][1], s1.z + o[rr2][2], s1.w + o[rr2][3]);
        o2 = make_float4(s2v.x + o[rr2][4], s2v.y + o[rr2][5], s2v.z + o[rr2][6], s2v.w + o[rr2][7]);
      }
      *(float4*)(out + idx)     = o1;
      *(float4*)(out + idx + 4) = o2;
    }
  }
}

__global__ void conv_w_kernel(const float* __restrict__ w, bf16_t* __restrict__ o) {
  int i = (blockIdx.x * blockDim.x + threadIdx.x) * 8;
  if (i < H_*H_) {
    float4 u = *(const float4*)(w + i);
    float4 v = *(const float4*)(w + i + 4);
    bf16x8 b;
    b[0]=(bf16_t)(u.x*SCAL); b[1]=(bf16_t)(u.y*SCAL); b[2]=(bf16_t)(u.z*SCAL); b[3]=(bf16_t)(u.w*SCAL);
    b[4]=(bf16_t)(v.x*SCAL); b[5]=(bf16_t)(v.y*SCAL); b[6]=(bf16_t)(v.z*SCAL); b[7]=(bf16_t)(v.w*SCAL);
    *(bf16x8*)(o + i) = b;
  }
}

extern "C" void kernel_launch(void* const* d_in, const int* in_sizes, int n_in,
                              void* d_out, int out_size, void* d_ws, size_t ws_size,
                              hipStream_t stream) {
  const float* seq    = (const float*)d_in[0];
  const float* lab    = (const float*)d_in[1];
  const float* attw   = (const float*)d_in[2];
  const float* attb   = (const float*)d_in[3];
  const float* fcw    = (const float*)d_in[4];
  const int*   counts = (const int*)d_in[5];
  float* out = (float*)d_out;

  if (ws_size >= (size_t)WS_NEED) {
    bf16_t* wbf = (bf16_t*)((char*)d_ws + WS_W_OFF);
    f16_t*  lsg = (f16_t*)((char*)d_ws + WS_LS_OFF);
    f16_t*  xsp = (f16_t*)((char*)d_ws + WS_XS_OFF);
    prep_kernel<<<dim3((H_*H_/8 + 255)/256), dim3(256), 0, stream>>>(attw, lab, attb, wbf, lsg);
    gemm_xs<<<dim3(ROWS/K1_BM), dim3(K1_NT), 0, stream>>>(seq, attb, wbf, xsp);
    score_ctx<<<dim3(ROWS/K2_R), dim3(256), 0, stream>>>(xsp, lsg, fcw, seq, lab, counts, out);
  } else if (ws_size >= (size_t)(H_*H_*2)) {
    bf16_t* wbf = (bf16_t*)d_ws;
    conv_w_kernel<<<dim3((H_*H_/8 + 255)/256), dim3(256), 0, stream>>>(attw, wbf);
    ner_fused<true><<<dim3(ROWS/BM), dim3(NT), 0, stream>>>(seq, lab, attw, attb, fcw, counts, wbf, out);
  } else {
    ner_fused<false><<<dim3(ROWS/BM), dim3(NT), 0, stream>>>(seq, lab, attw, attb, fcw, counts, nullptr, out);
  }
}